// Round 2
// baseline (1509.343 us; speedup 1.0000x reference)
//
#include <hip/hip_runtime.h>

#define NN 100000
#define CC 128
#define EE 200000
#define TT 3
#define NCHUNK 98   // ceil(NN/1024)

// ---------------- pack weights: WT[mat][k][c] = W[c][k], biases packed ----------------
__global__ __launch_bounds__(256) void k_pack(
    const float* __restrict__ Wq, const float* __restrict__ bq,
    const float* __restrict__ Wk, const float* __restrict__ bk,
    const float* __restrict__ Wv, const float* __restrict__ bv,
    const float* __restrict__ Ws, const float* __restrict__ bs,
    const float* __restrict__ Wf,
    float* __restrict__ WTpack, float* __restrict__ WfT, float* __restrict__ Bpack)
{
    int idx = blockIdx.x * 256 + threadIdx.x;   // 0..16383
    int y = blockIdx.y;
    if (y < 12) {
        int t = y >> 2, m = y & 3;
        const float* W = (m == 0 ? Wq : m == 1 ? Wk : m == 2 ? Wv : Ws) + t * CC * CC;
        int k = idx >> 7, c = idx & 127;
        WTpack[y * CC * CC + idx] = W[c * CC + k];
    } else if (y < 15) {
        int t = y - 12;
        int k = idx >> 7, c = idx & 127;
        WfT[t * CC * CC + idx] = Wf[c * (TT * CC) + t * CC + k];
    } else {
        if (idx < TT * 4 * CC) {
            int t = idx >> 9;
            int m = (idx >> 7) & 3;
            int c = idx & 127;
            const float* b = (m == 0 ? bq : m == 1 ? bk : m == 2 ? bv : bs);
            Bpack[idx] = b[t * CC + c];
        }
    }
}

// ---------------- CSR build ----------------
__global__ __launch_bounds__(256) void k_count(const int* __restrict__ dst, int* __restrict__ deg) {
    int idx = blockIdx.x * 256 + threadIdx.x;
    if (idx >= TT * EE) return;
    int t = idx / EE;
    atomicAdd(&deg[t * NN + dst[idx]], 1);
}

__global__ __launch_bounds__(256) void k_scan1(const int* __restrict__ deg,
                                               int* __restrict__ incl, int* __restrict__ bsums) {
    int t = blockIdx.y, b = blockIdx.x, tid = threadIdx.x;
    const int* d = deg + t * NN;
    int base = b * 1024 + tid * 4;
    int v0 = (base + 0 < NN) ? d[base + 0] : 0;
    int v1 = (base + 1 < NN) ? d[base + 1] : 0;
    int v2 = (base + 2 < NN) ? d[base + 2] : 0;
    int v3 = (base + 3 < NN) ? d[base + 3] : 0;
    v1 += v0; v2 += v1; v3 += v2;
    __shared__ int lds[256];
    lds[tid] = v3;
    for (int off = 1; off < 256; off <<= 1) {
        __syncthreads();
        int x = (tid >= off) ? lds[tid - off] : 0;
        __syncthreads();
        lds[tid] += x;
    }
    __syncthreads();
    int excl = lds[tid] - v3;
    if (base + 0 < NN) incl[t * NN + base + 0] = excl + v0;
    if (base + 1 < NN) incl[t * NN + base + 1] = excl + v1;
    if (base + 2 < NN) incl[t * NN + base + 2] = excl + v2;
    if (base + 3 < NN) incl[t * NN + base + 3] = excl + v3;
    if (tid == 255) bsums[t * NCHUNK + b] = lds[255];
}

__global__ __launch_bounds__(128) void k_scan2(const int* __restrict__ bsums, int* __restrict__ bexcl) {
    int t = blockIdx.y, tid = threadIdx.x;
    __shared__ int lds[128];
    int v = (tid < NCHUNK) ? bsums[t * NCHUNK + tid] : 0;
    lds[tid] = v;
    for (int off = 1; off < 128; off <<= 1) {
        __syncthreads();
        int x = (tid >= off) ? lds[tid - off] : 0;
        __syncthreads();
        lds[tid] += x;
    }
    if (tid < NCHUNK) bexcl[t * NCHUNK + tid] = lds[tid] - v;
}

__global__ __launch_bounds__(256) void k_scan3(const int* __restrict__ deg, const int* __restrict__ incl,
                                               const int* __restrict__ bexcl,
                                               int* __restrict__ offs, int* __restrict__ cursor) {
    int t = blockIdx.y, b = blockIdx.x, tid = threadIdx.x;
    int add = bexcl[t * NCHUNK + b];
    int base = b * 1024 + tid * 4;
    #pragma unroll
    for (int j = 0; j < 4; j++) {
        int i = base + j;
        if (i < NN) {
            int e = incl[t * NN + i] - deg[t * NN + i] + add;
            offs[t * NN + i] = e;
            cursor[t * NN + i] = e;
        }
    }
}

__global__ __launch_bounds__(256) void k_scatter(const int* __restrict__ src, const int* __restrict__ dst,
                                                 int* __restrict__ cursor, int* __restrict__ csr_src) {
    int idx = blockIdx.x * 256 + threadIdx.x;
    if (idx >= TT * EE) return;
    int t = idx / EE;
    int d = dst[idx];
    int pos = atomicAdd(&cursor[t * NN + d], 1);
    csr_src[t * EE + pos] = src[idx];
}

// ---------------- 4-way linear: Q,K,V,R(skip) for one edge type ----------------
__global__ __launch_bounds__(256) void k_gemm4(
    const float* __restrict__ x, const float* __restrict__ Wt, const float* __restrict__ B,
    float* __restrict__ Q, float* __restrict__ Kx, float* __restrict__ V, float* __restrict__ R)
{
    __shared__ float lx[32][132];
    __shared__ float lw[64][128];
    int tid = threadIdx.x;
    int base = blockIdx.x * 32;
    #pragma unroll
    for (int i = 0; i < 4; i++) {
        int f = tid + i * 256;
        int row = f >> 5, c4 = (f & 31) << 2;
        int gr = base + row;
        float4 val = make_float4(0.f, 0.f, 0.f, 0.f);
        if (gr < NN) val = *(const float4*)(x + (size_t)gr * CC + c4);
        *(float4*)&lx[row][c4] = val;
    }
    int cg = tid & 15, rg = tid >> 4;
    int c0 = cg << 3;
    int r0 = rg << 1, r1 = r0 | 1;
    for (int m = 0; m < 4; m++) {
        float acc[2][8];
        #pragma unroll
        for (int r = 0; r < 2; r++)
            #pragma unroll
            for (int j = 0; j < 8; j++) acc[r][j] = 0.f;
        for (int kh = 0; kh < 2; kh++) {
            __syncthreads();
            const float4* wsrc = (const float4*)(Wt + m * CC * CC + kh * 64 * CC);
            #pragma unroll
            for (int i = 0; i < 8; i++)
                ((float4*)lw)[tid + i * 256] = wsrc[tid + i * 256];
            __syncthreads();
            #pragma unroll
            for (int k = 0; k < 64; k += 4) {
                float4 xa = *(const float4*)&lx[r0][(kh << 6) + k];
                float4 xb = *(const float4*)&lx[r1][(kh << 6) + k];
                float fa[4] = {xa.x, xa.y, xa.z, xa.w};
                float fb[4] = {xb.x, xb.y, xb.z, xb.w};
                #pragma unroll
                for (int j = 0; j < 4; j++) {
                    float4 w0 = *(const float4*)&lw[k + j][c0];
                    float4 w1 = *(const float4*)&lw[k + j][c0 + 4];
                    acc[0][0] += fa[j] * w0.x; acc[0][1] += fa[j] * w0.y;
                    acc[0][2] += fa[j] * w0.z; acc[0][3] += fa[j] * w0.w;
                    acc[0][4] += fa[j] * w1.x; acc[0][5] += fa[j] * w1.y;
                    acc[0][6] += fa[j] * w1.z; acc[0][7] += fa[j] * w1.w;
                    acc[1][0] += fb[j] * w0.x; acc[1][1] += fb[j] * w0.y;
                    acc[1][2] += fb[j] * w0.z; acc[1][3] += fb[j] * w0.w;
                    acc[1][4] += fb[j] * w1.x; acc[1][5] += fb[j] * w1.y;
                    acc[1][6] += fb[j] * w1.z; acc[1][7] += fb[j] * w1.w;
                }
            }
        }
        float* dstp = (m == 0 ? Q : m == 1 ? Kx : m == 2 ? V : R);
        float4 b0 = *(const float4*)&B[m * CC + c0];
        float4 b1 = *(const float4*)&B[m * CC + c0 + 4];
        int gr0 = base + r0, gr1 = base + r1;
        if (gr0 < NN) {
            float4 o0 = make_float4(acc[0][0] + b0.x, acc[0][1] + b0.y, acc[0][2] + b0.z, acc[0][3] + b0.w);
            float4 o1 = make_float4(acc[0][4] + b1.x, acc[0][5] + b1.y, acc[0][6] + b1.z, acc[0][7] + b1.w);
            *(float4*)(dstp + (size_t)gr0 * CC + c0) = o0;
            *(float4*)(dstp + (size_t)gr0 * CC + c0 + 4) = o1;
        }
        if (gr1 < NN) {
            float4 o0 = make_float4(acc[1][0] + b0.x, acc[1][1] + b0.y, acc[1][2] + b0.z, acc[1][3] + b0.w);
            float4 o1 = make_float4(acc[1][4] + b1.x, acc[1][5] + b1.y, acc[1][6] + b1.z, acc[1][7] + b1.w);
            *(float4*)(dstp + (size_t)gr1 * CC + c0) = o0;
            *(float4*)(dstp + (size_t)gr1 * CC + c0 + 4) = o1;
        }
    }
}

// ---------------- per-(node) attention aggregation, one wave per node ----------------
__global__ __launch_bounds__(256) void k_agg(
    const float* __restrict__ Q, const float* __restrict__ Kx,
    const float* __restrict__ V, float* __restrict__ R,
    const int* __restrict__ offs, const int* __restrict__ deg, const int* __restrict__ csr)
{
    int wid = threadIdx.x >> 6;
    int lane = threadIdx.x & 63;
    int n = blockIdx.x * 4 + wid;
    if (n >= NN) return;
    int dg = deg[n];
    if (dg == 0) return;   // keep skip-only value in R
    const float scale = 0.17677669529663687f;  // 1/sqrt(32)
    float q0 = Q[n * CC + lane];
    float q1 = Q[n * CC + 64 + lane];
    float acc0 = 0.f, acc1 = 0.f, den0 = 0.f, den1 = 0.f;
    int off = offs[n];
    for (int i = 0; i < dg; i++) {
        int s = csr[off + i];
        const float* kb = Kx + (size_t)s * CC;
        const float* vb = V + (size_t)s * CC;
        float k0 = kb[lane], k1 = kb[64 + lane];
        float v0 = vb[lane], v1 = vb[64 + lane];
        float d0 = q0 * k0, d1 = q1 * k1;
        #pragma unroll
        for (int m = 16; m >= 1; m >>= 1) {
            d0 += __shfl_xor(d0, m);
            d1 += __shfl_xor(d1, m);
        }
        float e0 = expf(d0 * scale), e1 = expf(d1 * scale);
        acc0 += e0 * v0; den0 += e0;
        acc1 += e1 * v1; den1 += e1;
    }
    R[(size_t)n * CC + lane]      += acc0 / (den0 + 1e-16f);
    R[(size_t)n * CC + 64 + lane] += acc1 / (den1 + 1e-16f);
}

// ---------------- fusion: out (+)= R @ WfT_t (+ bf) ----------------
__global__ __launch_bounds__(256) void k_fuse(
    const float* __restrict__ Rin, const float* __restrict__ Wt,
    const float* __restrict__ bf, float* __restrict__ out, int add)
{
    __shared__ float lx[32][132];
    __shared__ float lw[64][128];
    int tid = threadIdx.x;
    int base = blockIdx.x * 32;
    #pragma unroll
    for (int i = 0; i < 4; i++) {
        int f = tid + i * 256;
        int row = f >> 5, c4 = (f & 31) << 2;
        int gr = base + row;
        float4 val = make_float4(0.f, 0.f, 0.f, 0.f);
        if (gr < NN) val = *(const float4*)(Rin + (size_t)gr * CC + c4);
        *(float4*)&lx[row][c4] = val;
    }
    int cg = tid & 15, rg = tid >> 4;
    int c0 = cg << 3;
    int r0 = rg << 1, r1 = r0 | 1;
    float acc[2][8];
    #pragma unroll
    for (int r = 0; r < 2; r++)
        #pragma unroll
        for (int j = 0; j < 8; j++) acc[r][j] = 0.f;
    for (int kh = 0; kh < 2; kh++) {
        __syncthreads();
        const float4* wsrc = (const float4*)(Wt + kh * 64 * CC);
        #pragma unroll
        for (int i = 0; i < 8; i++)
            ((float4*)lw)[tid + i * 256] = wsrc[tid + i * 256];
        __syncthreads();
        #pragma unroll
        for (int k = 0; k < 64; k += 4) {
            float4 xa = *(const float4*)&lx[r0][(kh << 6) + k];
            float4 xb = *(const float4*)&lx[r1][(kh << 6) + k];
            float fa[4] = {xa.x, xa.y, xa.z, xa.w};
            float fb[4] = {xb.x, xb.y, xb.z, xb.w};
            #pragma unroll
            for (int j = 0; j < 4; j++) {
                float4 w0 = *(const float4*)&lw[k + j][c0];
                float4 w1 = *(const float4*)&lw[k + j][c0 + 4];
                acc[0][0] += fa[j] * w0.x; acc[0][1] += fa[j] * w0.y;
                acc[0][2] += fa[j] * w0.z; acc[0][3] += fa[j] * w0.w;
                acc[0][4] += fa[j] * w1.x; acc[0][5] += fa[j] * w1.y;
                acc[0][6] += fa[j] * w1.z; acc[0][7] += fa[j] * w1.w;
                acc[1][0] += fb[j] * w0.x; acc[1][1] += fb[j] * w0.y;
                acc[1][2] += fb[j] * w0.z; acc[1][3] += fb[j] * w0.w;
                acc[1][4] += fb[j] * w1.x; acc[1][5] += fb[j] * w1.y;
                acc[1][6] += fb[j] * w1.z; acc[1][7] += fb[j] * w1.w;
            }
        }
    }
    int gr0 = base + r0, gr1 = base + r1;
    if (add) {
        if (gr0 < NN) {
            float4 o0 = *(float4*)(out + (size_t)gr0 * CC + c0);
            float4 o1 = *(float4*)(out + (size_t)gr0 * CC + c0 + 4);
            o0.x += acc[0][0]; o0.y += acc[0][1]; o0.z += acc[0][2]; o0.w += acc[0][3];
            o1.x += acc[0][4]; o1.y += acc[0][5]; o1.z += acc[0][6]; o1.w += acc[0][7];
            *(float4*)(out + (size_t)gr0 * CC + c0) = o0;
            *(float4*)(out + (size_t)gr0 * CC + c0 + 4) = o1;
        }
        if (gr1 < NN) {
            float4 o0 = *(float4*)(out + (size_t)gr1 * CC + c0);
            float4 o1 = *(float4*)(out + (size_t)gr1 * CC + c0 + 4);
            o0.x += acc[1][0]; o0.y += acc[1][1]; o0.z += acc[1][2]; o0.w += acc[1][3];
            o1.x += acc[1][4]; o1.y += acc[1][5]; o1.z += acc[1][6]; o1.w += acc[1][7];
            *(float4*)(out + (size_t)gr1 * CC + c0) = o0;
            *(float4*)(out + (size_t)gr1 * CC + c0 + 4) = o1;
        }
    } else {
        float4 b0 = *(const float4*)&bf[c0];
        float4 b1 = *(const float4*)&bf[c0 + 4];
        if (gr0 < NN) {
            float4 o0 = make_float4(acc[0][0] + b0.x, acc[0][1] + b0.y, acc[0][2] + b0.z, acc[0][3] + b0.w);
            float4 o1 = make_float4(acc[0][4] + b1.x, acc[0][5] + b1.y, acc[0][6] + b1.z, acc[0][7] + b1.w);
            *(float4*)(out + (size_t)gr0 * CC + c0) = o0;
            *(float4*)(out + (size_t)gr0 * CC + c0 + 4) = o1;
        }
        if (gr1 < NN) {
            float4 o0 = make_float4(acc[1][0] + b0.x, acc[1][1] + b0.y, acc[1][2] + b0.z, acc[1][3] + b0.w);
            float4 o1 = make_float4(acc[1][4] + b1.x, acc[1][5] + b1.y, acc[1][6] + b1.z, acc[1][7] + b1.w);
            *(float4*)(out + (size_t)gr1 * CC + c0) = o0;
            *(float4*)(out + (size_t)gr1 * CC + c0 + 4) = o1;
        }
    }
}

extern "C" void kernel_launch(void* const* d_in, const int* in_sizes, int n_in,
                              void* d_out, int out_size, void* d_ws, size_t ws_size,
                              hipStream_t stream)
{
    const float* x   = (const float*)d_in[0];
    const int*   src = (const int*)d_in[1];
    const int*   dst = (const int*)d_in[2];
    const float* Wq  = (const float*)d_in[3];
    const float* bq  = (const float*)d_in[4];
    const float* Wk  = (const float*)d_in[5];
    const float* bk  = (const float*)d_in[6];
    const float* Wv  = (const float*)d_in[7];
    const float* bv  = (const float*)d_in[8];
    const float* Ws  = (const float*)d_in[9];
    const float* bs  = (const float*)d_in[10];
    const float* Wf  = (const float*)d_in[11];
    const float* bf  = (const float*)d_in[12];
    float* out = (float*)d_out;

    char* ws = (char*)d_ws;
    size_t o = 0;
    auto alloc = [&](size_t bytes) -> char* {
        char* p = ws + o;
        o = (o + bytes + 255) & ~(size_t)255;
        return p;
    };
    float* WTpack = (float*)alloc((size_t)12 * CC * CC * 4);
    float* WfT    = (float*)alloc((size_t)3 * CC * CC * 4);
    float* Bpack  = (float*)alloc((size_t)12 * CC * 4);
    int* deg      = (int*)alloc((size_t)TT * NN * 4);
    int* incl     = (int*)alloc((size_t)TT * NN * 4);
    int* bsums    = (int*)alloc((size_t)TT * NCHUNK * 4);
    int* bexcl    = (int*)alloc((size_t)TT * NCHUNK * 4);
    int* offs     = (int*)alloc((size_t)TT * NN * 4);
    int* cursor   = (int*)alloc((size_t)TT * NN * 4);
    int* csr_src  = (int*)alloc((size_t)TT * EE * 4);
    float* Qb = (float*)alloc((size_t)NN * CC * 4);
    float* Kb = (float*)alloc((size_t)NN * CC * 4);
    float* Vb = (float*)alloc((size_t)NN * CC * 4);
    float* Rb = (float*)alloc((size_t)NN * CC * 4);

    hipMemsetAsync(deg, 0, (size_t)TT * NN * 4, stream);
    k_pack<<<dim3(64, 16), 256, 0, stream>>>(Wq, bq, Wk, bk, Wv, bv, Ws, bs, Wf, WTpack, WfT, Bpack);
    k_count<<<(TT * EE + 255) / 256, 256, 0, stream>>>(dst, deg);
    k_scan1<<<dim3(NCHUNK, TT), 256, 0, stream>>>(deg, incl, bsums);
    k_scan2<<<dim3(1, TT), 128, 0, stream>>>(bsums, bexcl);
    k_scan3<<<dim3(NCHUNK, TT), 256, 0, stream>>>(deg, incl, bexcl, offs, cursor);
    k_scatter<<<(TT * EE + 255) / 256, 256, 0, stream>>>(src, dst, cursor, csr_src);

    int gblocks = (NN + 31) / 32;
    for (int t = 0; t < TT; t++) {
        k_gemm4<<<gblocks, 256, 0, stream>>>(x, WTpack + (size_t)t * 4 * CC * CC, Bpack + t * 4 * CC,
                                             Qb, Kb, Vb, Rb);
        k_agg<<<(NN + 3) / 4, 256, 0, stream>>>(Qb, Kb, Vb, Rb,
                                                offs + t * NN, deg + t * NN, csr_src + (size_t)t * EE);
        k_fuse<<<gblocks, 256, 0, stream>>>(Rb, WfT + (size_t)t * CC * CC, bf, out, t == 0 ? 0 : 1);
    }
}

// Round 5
// 1177.605 us; speedup vs baseline: 1.2817x; 1.2817x over previous
//
#include <hip/hip_runtime.h>

#define NN 100000
#define CC 128
#define EE 200000
#define TT 3
#define NCHUNK 98   // ceil(NN/1024)
#define LXW 18      // lx row stride (16 + 2 pad) -> a-read banks spread by 8

// ---------------- pack weights: WT3[(t*3+m)][k][c] = W[c][k]; WfT[t][k][c]; biases ----------------
__global__ __launch_bounds__(256) void k_pack(
    const float* __restrict__ Wq, const float* __restrict__ bq,
    const float* __restrict__ Wk, const float* __restrict__ bk,
    const float* __restrict__ Wv, const float* __restrict__ bv,
    const float* __restrict__ Wf,
    float* __restrict__ WT3, float* __restrict__ WfT, float* __restrict__ Bpack)
{
    int idx = blockIdx.x * 256 + threadIdx.x;   // 0..16383
    int y = blockIdx.y;                          // 0..12
    if (y < 9) {
        int t = y / 3, m = y % 3;
        const float* W = (m == 0 ? Wq : m == 1 ? Wk : Wv) + t * CC * CC;
        int k = idx >> 7, c = idx & 127;
        WT3[y * CC * CC + idx] = W[c * CC + k];
    } else if (y < 12) {
        int t = y - 9;
        int k = idx >> 7, c = idx & 127;
        WfT[t * CC * CC + idx] = Wf[c * (TT * CC) + t * CC + k];
    } else {
        if (idx < 9 * CC) {
            int mm = idx >> 7, c = idx & 127;
            int t = mm / 3, m = mm % 3;
            const float* b = (m == 0 ? bq : m == 1 ? bk : bv);
            Bpack[idx] = b[t * CC + c];
        }
    }
}

// ---------------- Wcomb[k][c] = sum_t sum_j Ws[t][j][k]*Wf[c][t*128+j]; bconst ----------------
__global__ __launch_bounds__(256) void k_wcomb(
    const float* __restrict__ Ws, const float* __restrict__ bs,
    const float* __restrict__ Wf, const float* __restrict__ bf,
    float* __restrict__ Wcomb, float* __restrict__ bconst)
{
    int b = blockIdx.x;
    if (b < 64) {
        int idx = b * 256 + threadIdx.x;
        int k = idx >> 7, c = idx & 127;
        float s = 0.f;
        for (int t = 0; t < TT; ++t) {
            const float* wsp = Ws + t * CC * CC;
            const float* wfp = Wf + (size_t)c * (TT * CC) + t * CC;
            for (int j = 0; j < CC; ++j)
                s += wsp[j * CC + k] * wfp[j];
        }
        Wcomb[k * CC + c] = s;
    } else {
        int c = threadIdx.x;
        if (c < CC) {
            float s = bf[c];
            for (int t = 0; t < TT; ++t) {
                const float* wfp = Wf + (size_t)c * (TT * CC) + t * CC;
                for (int j = 0; j < CC; ++j)
                    s += bs[t * CC + j] * wfp[j];
            }
            bconst[c] = s;
        }
    }
}

// ---------------- CSR build ----------------
__global__ __launch_bounds__(256) void k_count(const int* __restrict__ dst, int* __restrict__ deg) {
    int idx = blockIdx.x * 256 + threadIdx.x;
    if (idx >= TT * EE) return;
    int t = idx / EE;
    atomicAdd(&deg[t * NN + dst[idx]], 1);
}

__global__ __launch_bounds__(256) void k_scan1(const int* __restrict__ deg,
                                               int* __restrict__ incl, int* __restrict__ bsums) {
    int t = blockIdx.y, b = blockIdx.x, tid = threadIdx.x;
    const int* d = deg + t * NN;
    int base = b * 1024 + tid * 4;
    int v0 = (base + 0 < NN) ? d[base + 0] : 0;
    int v1 = (base + 1 < NN) ? d[base + 1] : 0;
    int v2 = (base + 2 < NN) ? d[base + 2] : 0;
    int v3 = (base + 3 < NN) ? d[base + 3] : 0;
    v1 += v0; v2 += v1; v3 += v2;
    __shared__ int lds[256];
    lds[tid] = v3;
    for (int off = 1; off < 256; off <<= 1) {
        __syncthreads();
        int x = (tid >= off) ? lds[tid - off] : 0;
        __syncthreads();
        lds[tid] += x;
    }
    __syncthreads();
    int excl = lds[tid] - v3;
    if (base + 0 < NN) incl[t * NN + base + 0] = excl + v0;
    if (base + 1 < NN) incl[t * NN + base + 1] = excl + v1;
    if (base + 2 < NN) incl[t * NN + base + 2] = excl + v2;
    if (base + 3 < NN) incl[t * NN + base + 3] = excl + v3;
    if (tid == 255) bsums[t * NCHUNK + b] = lds[255];
}

__global__ __launch_bounds__(128) void k_scan2(const int* __restrict__ bsums, int* __restrict__ bexcl) {
    int t = blockIdx.y, tid = threadIdx.x;
    __shared__ int lds[128];
    int v = (tid < NCHUNK) ? bsums[t * NCHUNK + tid] : 0;
    lds[tid] = v;
    for (int off = 1; off < 128; off <<= 1) {
        __syncthreads();
        int x = (tid >= off) ? lds[tid - off] : 0;
        __syncthreads();
        lds[tid] += x;
    }
    if (tid < NCHUNK) bexcl[t * NCHUNK + tid] = lds[tid] - v;
}

__global__ __launch_bounds__(256) void k_scan3(const int* __restrict__ deg, const int* __restrict__ incl,
                                               const int* __restrict__ bexcl,
                                               int* __restrict__ offs, int* __restrict__ cursor) {
    int t = blockIdx.y, b = blockIdx.x, tid = threadIdx.x;
    int add = bexcl[t * NCHUNK + b];
    int base = b * 1024 + tid * 4;
    #pragma unroll
    for (int j = 0; j < 4; j++) {
        int i = base + j;
        if (i < NN) {
            int e = incl[t * NN + i] - deg[t * NN + i] + add;
            offs[t * NN + i] = e;
            cursor[t * NN + i] = e;
        }
    }
}

__global__ __launch_bounds__(256) void k_scatter(const int* __restrict__ src, const int* __restrict__ dst,
                                                 int* __restrict__ cursor, int* __restrict__ csr_src) {
    int idx = blockIdx.x * 256 + threadIdx.x;
    if (idx >= TT * EE) return;
    int t = idx / EE;
    int d = dst[idx];
    int pos = atomicAdd(&cursor[t * NN + d], 1);
    csr_src[t * EE + pos] = src[idx];
}

// ---------------- GEMM inner tiles ----------------
// lx: [64][LXW] (k-chunk of 16), lw3: [3][16][128], per-thread 4 rows x (4+4) cols
__device__ __forceinline__ void mm3(float acc[3][4][8], const float* lx, const float* lw,
                                    int r0, int c0)
{
    #pragma unroll
    for (int k4 = 0; k4 < 4; ++k4) {
        float4 a[4];
        #pragma unroll
        for (int r = 0; r < 4; ++r)
            a[r] = *(const float4*)(lx + (r0 + r) * LXW + (k4 << 2));
        #pragma unroll
        for (int m = 0; m < 3; ++m) {
            #pragma unroll
            for (int kk = 0; kk < 4; ++kk) {
                const float* wrow = lw + (((m << 4) + (k4 << 2) + kk) << 7);
                float4 b0 = *(const float4*)(wrow + c0);
                float4 b1 = *(const float4*)(wrow + 64 + c0);
                #pragma unroll
                for (int r = 0; r < 4; ++r) {
                    float av = (kk == 0 ? a[r].x : kk == 1 ? a[r].y : kk == 2 ? a[r].z : a[r].w);
                    acc[m][r][0] += av * b0.x; acc[m][r][1] += av * b0.y;
                    acc[m][r][2] += av * b0.z; acc[m][r][3] += av * b0.w;
                    acc[m][r][4] += av * b1.x; acc[m][r][5] += av * b1.y;
                    acc[m][r][6] += av * b1.z; acc[m][r][7] += av * b1.w;
                }
            }
        }
    }
}

__device__ __forceinline__ void mm1(float acc[4][8], const float* lx, const float* lw,
                                    int r0, int c0)
{
    #pragma unroll
    for (int k4 = 0; k4 < 4; ++k4) {
        float4 a[4];
        #pragma unroll
        for (int r = 0; r < 4; ++r)
            a[r] = *(const float4*)(lx + (r0 + r) * LXW + (k4 << 2));
        #pragma unroll
        for (int kk = 0; kk < 4; ++kk) {
            const float* wrow = lw + (((k4 << 2) + kk) << 7);
            float4 b0 = *(const float4*)(wrow + c0);
            float4 b1 = *(const float4*)(wrow + 64 + c0);
            #pragma unroll
            for (int r = 0; r < 4; ++r) {
                float av = (kk == 0 ? a[r].x : kk == 1 ? a[r].y : kk == 2 ? a[r].z : a[r].w);
                acc[r][0] += av * b0.x; acc[r][1] += av * b0.y;
                acc[r][2] += av * b0.z; acc[r][3] += av * b0.w;
                acc[r][4] += av * b1.x; acc[r][5] += av * b1.y;
                acc[r][6] += av * b1.z; acc[r][7] += av * b1.w;
            }
        }
    }
}

// ---------------- Q,K,V for one type: 64x128 tile, k-chunks of 16 ----------------
__global__ __launch_bounds__(256) void k_gemm3(
    const float* __restrict__ x, const float* __restrict__ W3, const float* __restrict__ B3,
    float* __restrict__ Q, float* __restrict__ Kq, float* __restrict__ V)
{
    __shared__ float lx[64 * LXW];
    __shared__ float lw[3 * 16 * 128];
    int tid = threadIdx.x;
    int base = blockIdx.x * 64;
    int tc = tid & 15, tr = tid >> 4;
    int c0 = tc << 2, r0 = tr << 2;
    float acc[3][4][8];
    #pragma unroll
    for (int m = 0; m < 3; ++m)
        #pragma unroll
        for (int r = 0; r < 4; ++r)
            #pragma unroll
            for (int j = 0; j < 8; ++j) acc[m][r][j] = 0.f;

    for (int kc = 0; kc < 8; ++kc) {
        __syncthreads();
        {   // stage x chunk: 64 rows x 16 k (one float4/thread)
            int row = tid >> 2, c4 = (tid & 3) << 2;
            int gr = base + row;
            float4 v = make_float4(0.f, 0.f, 0.f, 0.f);
            if (gr < NN) v = *(const float4*)(x + (size_t)gr * CC + (kc << 4) + c4);
            *(float4*)&lx[row * LXW + c4] = v;
        }
        #pragma unroll
        for (int i = 0; i < 6; ++i) {   // stage 3 x (16x128) W chunk
            int f = tid + i * 256;      // f4 index 0..1535
            int m = f >> 9, rem = f & 511;
            *(float4*)&lw[(m << 11) + (rem << 2)] =
                *(const float4*)(W3 + m * CC * CC + (kc << 11) + (rem << 2));
        }
        __syncthreads();
        mm3(acc, lx, lw, r0, c0);
    }

    #pragma unroll
    for (int m = 0; m < 3; ++m) {
        float* dst = (m == 0 ? Q : m == 1 ? Kq : V);
        float4 b0 = *(const float4*)(B3 + (m << 7) + c0);
        float4 b1 = *(const float4*)(B3 + (m << 7) + 64 + c0);
        #pragma unroll
        for (int r = 0; r < 4; ++r) {
            int gr = base + r0 + r;
            if (gr < NN) {
                float4 o0 = make_float4(acc[m][r][0] + b0.x, acc[m][r][1] + b0.y,
                                        acc[m][r][2] + b0.z, acc[m][r][3] + b0.w);
                float4 o1 = make_float4(acc[m][r][4] + b1.x, acc[m][r][5] + b1.y,
                                        acc[m][r][6] + b1.z, acc[m][r][7] + b1.w);
                *(float4*)(dst + (size_t)gr * CC + c0) = o0;
                *(float4*)(dst + (size_t)gr * CC + 64 + c0) = o1;
            }
        }
    }
}

// ---------------- fusion: out (+)= X0@W0 [+ X1@W1] (+ bconst) ----------------
__global__ __launch_bounds__(256) void k_fuse2(
    const float* __restrict__ X0, const float* __restrict__ W0,
    const float* __restrict__ X1, const float* __restrict__ W1,
    const float* __restrict__ bias, float* __restrict__ out, int accum)
{
    __shared__ float lx[64 * LXW];
    __shared__ float lw[16 * 128];
    int tid = threadIdx.x;
    int base = blockIdx.x * 64;
    int tc = tid & 15, tr = tid >> 4;
    int c0 = tc << 2, r0 = tr << 2;
    float acc[4][8];
    #pragma unroll
    for (int r = 0; r < 4; ++r)
        #pragma unroll
        for (int j = 0; j < 8; ++j) acc[r][j] = 0.f;

    #pragma unroll 1
    for (int s = 0; s < 2; ++s) {
        const float* X = s ? X1 : X0;
        const float* W = s ? W1 : W0;
        if (!X) break;
        for (int kc = 0; kc < 8; ++kc) {
            __syncthreads();
            {
                int row = tid >> 2, c4 = (tid & 3) << 2;
                int gr = base + row;
                float4 v = make_float4(0.f, 0.f, 0.f, 0.f);
                if (gr < NN) v = *(const float4*)(X + (size_t)gr * CC + (kc << 4) + c4);
                *(float4*)&lx[row * LXW + c4] = v;
            }
            #pragma unroll
            for (int i = 0; i < 2; ++i) {
                int f = tid + i * 256;
                *(float4*)&lw[f << 2] = *(const float4*)(W + (kc << 11) + (f << 2));
            }
            __syncthreads();
            mm1(acc, lx, lw, r0, c0);
        }
    }

    #pragma unroll
    for (int r = 0; r < 4; ++r) {
        int gr = base + r0 + r;
        if (gr >= NN) continue;
        float4 o0 = make_float4(acc[r][0], acc[r][1], acc[r][2], acc[r][3]);
        float4 o1 = make_float4(acc[r][4], acc[r][5], acc[r][6], acc[r][7]);
        float* op0 = out + (size_t)gr * CC + c0;
        float* op1 = out + (size_t)gr * CC + 64 + c0;
        if (accum) {
            float4 p0 = *(float4*)op0, p1 = *(float4*)op1;
            o0.x += p0.x; o0.y += p0.y; o0.z += p0.z; o0.w += p0.w;
            o1.x += p1.x; o1.y += p1.y; o1.z += p1.z; o1.w += p1.w;
        } else {
            float4 b0 = *(const float4*)(bias + c0);
            float4 b1 = *(const float4*)(bias + 64 + c0);
            o0.x += b0.x; o0.y += b0.y; o0.z += b0.z; o0.w += b0.w;
            o1.x += b1.x; o1.y += b1.y; o1.z += b1.z; o1.w += b1.w;
        }
        *(float4*)op0 = o0;
        *(float4*)op1 = o1;
    }
}

// ---------------- per-node attention aggregation -> A (no skip) ----------------
__global__ __launch_bounds__(256) void k_agg(
    const float* __restrict__ Q, const float* __restrict__ Kx,
    const float* __restrict__ V, float* __restrict__ A,
    const int* __restrict__ offs, const int* __restrict__ deg, const int* __restrict__ csr)
{
    int wid = threadIdx.x >> 6;
    int lane = threadIdx.x & 63;
    int n = blockIdx.x * 4 + wid;
    if (n >= NN) return;
    int dg = deg[n];
    if (dg == 0) {
        A[(size_t)n * CC + lane] = 0.f;
        A[(size_t)n * CC + 64 + lane] = 0.f;
        return;
    }
    const float scale = 0.17677669529663687f;  // 1/sqrt(32)
    float q0 = Q[(size_t)n * CC + lane];
    float q1 = Q[(size_t)n * CC + 64 + lane];
    float acc0 = 0.f, acc1 = 0.f, den0 = 0.f, den1 = 0.f;
    int off = offs[n];
    for (int i = 0; i < dg; i++) {
        int s = csr[off + i];
        const float* kb = Kx + (size_t)s * CC;
        const float* vb = V + (size_t)s * CC;
        float k0 = kb[lane], k1 = kb[64 + lane];
        float v0 = vb[lane], v1 = vb[64 + lane];
        float d0 = q0 * k0, d1 = q1 * k1;
        #pragma unroll
        for (int m = 16; m >= 1; m >>= 1) {
            d0 += __shfl_xor(d0, m);
            d1 += __shfl_xor(d1, m);
        }
        float e0 = expf(d0 * scale), e1 = expf(d1 * scale);
        acc0 += e0 * v0; den0 += e0;
        acc1 += e1 * v1; den1 += e1;
    }
    A[(size_t)n * CC + lane]      = acc0 / (den0 + 1e-16f);
    A[(size_t)n * CC + 64 + lane] = acc1 / (den1 + 1e-16f);
}

extern "C" void kernel_launch(void* const* d_in, const int* in_sizes, int n_in,
                              void* d_out, int out_size, void* d_ws, size_t ws_size,
                              hipStream_t stream)
{
    const float* x   = (const float*)d_in[0];
    const int*   src = (const int*)d_in[1];
    const int*   dst = (const int*)d_in[2];
    const float* Wq  = (const float*)d_in[3];
    const float* bq  = (const float*)d_in[4];
    const float* Wk  = (const float*)d_in[5];
    const float* bk  = (const float*)d_in[6];
    const float* Wv  = (const float*)d_in[7];
    const float* bv  = (const float*)d_in[8];
    const float* Ws  = (const float*)d_in[9];
    const float* bs  = (const float*)d_in[10];
    const float* Wf  = (const float*)d_in[11];
    const float* bf  = (const float*)d_in[12];
    float* out = (float*)d_out;

    char* ws = (char*)d_ws;
    size_t o = 0;
    auto alloc = [&](size_t bytes) -> char* {
        char* p = ws + o;
        o = (o + bytes + 255) & ~(size_t)255;
        return p;
    };
    float* WT3    = (float*)alloc((size_t)9 * CC * CC * 4);
    float* WfT    = (float*)alloc((size_t)3 * CC * CC * 4);
    float* Wcomb  = (float*)alloc((size_t)CC * CC * 4);
    float* Bpack  = (float*)alloc((size_t)9 * CC * 4);
    float* bconst = (float*)alloc((size_t)CC * 4);
    int* deg      = (int*)alloc((size_t)TT * NN * 4);
    int* incl     = (int*)alloc((size_t)TT * NN * 4);
    int* bsums    = (int*)alloc((size_t)TT * NCHUNK * 4);
    int* bexcl    = (int*)alloc((size_t)TT * NCHUNK * 4);
    int* offs     = (int*)alloc((size_t)TT * NN * 4);
    int* cursor   = (int*)alloc((size_t)TT * NN * 4);
    int* csr_src  = (int*)alloc((size_t)TT * EE * 4);
    float* Qb = (float*)alloc((size_t)NN * CC * 4);
    float* Kb = (float*)alloc((size_t)NN * CC * 4);
    float* Vb = (float*)alloc((size_t)NN * CC * 4);
    float* Ab = (float*)alloc((size_t)NN * CC * 4);

    hipMemsetAsync(deg, 0, (size_t)TT * NN * 4, stream);
    k_pack<<<dim3(64, 13), 256, 0, stream>>>(Wq, bq, Wk, bk, Wv, bv, Wf, WT3, WfT, Bpack);
    k_wcomb<<<65, 256, 0, stream>>>(Ws, bs, Wf, bf, Wcomb, bconst);
    k_count<<<(TT * EE + 255) / 256, 256, 0, stream>>>(dst, deg);
    k_scan1<<<dim3(NCHUNK, TT), 256, 0, stream>>>(deg, incl, bsums);
    k_scan2<<<dim3(1, TT), 128, 0, stream>>>(bsums, bexcl);
    k_scan3<<<dim3(NCHUNK, TT), 256, 0, stream>>>(deg, incl, bexcl, offs, cursor);
    k_scatter<<<(TT * EE + 255) / 256, 256, 0, stream>>>(src, dst, cursor, csr_src);

    int gblocks = (NN + 63) / 64;
    for (int t = 0; t < TT; t++) {
        k_gemm3<<<gblocks, 256, 0, stream>>>(x, WT3 + (size_t)t * 3 * CC * CC, Bpack + t * 3 * CC,
                                             Qb, Kb, Vb);
        k_agg<<<(NN + 3) / 4, 256, 0, stream>>>(Qb, Kb, Vb, Ab,
                                                offs + t * NN, deg + t * NN, csr_src + (size_t)t * EE);
        if (t == 0)
            k_fuse2<<<gblocks, 256, 0, stream>>>(x, Wcomb, Ab, WfT, bconst, out, 0);
        else
            k_fuse2<<<gblocks, 256, 0, stream>>>(Ab, WfT + (size_t)t * CC * CC, nullptr, nullptr,
                                                 bconst, out, 1);
    }
}